// Round 16
// baseline (120.960 us; speedup 1.0000x reference)
//
#include <hip/hip_runtime.h>

// NTK-SVGP forward: D=H=128, C=10, N=256, M=128, T=128, sigma2=1, delta=1
#define H 128
#define DD 128
#define CC 10
#define NX 256
#define MZ 128
#define TN 128
#define S_TOT 512
#define SCALE (1.0f/256.0f)
#define JIT 1e-3f
#define INV_S2 1.0f

// ---------------- ws layout (float offsets) ----------------
#define OFF_XS    0u
#define OFF_A1    (OFF_XS   + S_TOT*DD)
#define OFF_A2    (OFF_A1   + S_TOT*H)
#define OFF_G1    (OFF_A2   + S_TOT*H)
#define OFF_G2    (OFF_G1   + S_TOT*CC*H)
#define OFF_BASE  (OFF_G2   + S_TOT*CC*H)
#define BASE_ZX   0u
#define BASE_ZZ   (3u*MZ*NX)
#define BASE_TZ   (3u*MZ*NX + 3u*MZ*MZ)
#define OFF_KZX   (OFF_BASE + 3u*MZ*NX + 3u*MZ*MZ + 3u*TN*MZ)
#define OFF_KZZ   (OFF_KZX  + CC*MZ*NX)
#define OFF_KXZ   (OFF_KZZ  + CC*MZ*MZ)
#define OFF_KZZJ  (OFF_KXZ  + CC*TN*MZ)
#define OFF_KZZB  (OFF_KZZJ + CC*MZ*MZ)
#define OFF_LAMU  (OFF_KZZB + CC*MZ*MZ)
#define OFF_LC    (OFF_LAMU + CC*MZ)
#define OFF_INVD  (OFF_LC   + 2u*CC*MZ*MZ)
#define OFF_YLAM  (OFF_INVD + 2u*CC*MZ)

// wave-reduce val over 64 lanes; lane0 of each wave writes partG[qi*2 + waveIdx]
#define WRED(val, qi) { float v_ = (val);                                     \
  v_ += __shfl_down(v_,32,64); v_ += __shfl_down(v_,16,64);                   \
  v_ += __shfl_down(v_, 8,64); v_ += __shfl_down(v_, 4,64);                   \
  v_ += __shfl_down(v_, 2,64); v_ += __shfl_down(v_, 1,64);                   \
  if ((h & 63) == 0) partG[(qi)*2 + (h>>6)] = v_; }

// Per-sample forward + backprop features. One block per sample, 128 threads.
// - W2 staged to LDS TRANSPOSED once per block (pad 129 -> conflict-free):
//   both the layer-2 matvec and the G1 backprop loop read LDS, eliminating
//   the 512B-stride divergent global reads that made R14's version 42us.
// - Test-sample blocks emit Kxx_diag into out's f_var half via the
//   single-barrier WRED reduction (verified in R13's mega P1).
// - Block s==0 zeroes LamU (k_gram, a later launch, atomicAdds into it).
__global__ __launch_bounds__(128) void k_features(
    const float* __restrict__ X, const float* __restrict__ Z, const float* __restrict__ Xt,
    const float* __restrict__ W1, const float* __restrict__ b1,
    const float* __restrict__ W2, const float* __restrict__ b2,
    const float* __restrict__ W3,
    float* __restrict__ XS, float* __restrict__ A1, float* __restrict__ A2,
    float* __restrict__ G1, float* __restrict__ G2, float* __restrict__ LamU,
    float* __restrict__ out)
{
  int s = blockIdx.x, h = threadIdx.x;
  __shared__ float xs[DD], a1s[H], g2s[CC*H];
  __shared__ float w2t[H*129];   // w2t[c*129 + r] = W2[r][c]
  __shared__ float partG[46];
  if (s == 0) {
    #pragma unroll
    for (int c = 0; c < CC; ++c) LamU[c*MZ + h] = 0.0f;
  }
  const float* xin = (s < NX) ? X + s*DD : (s < NX+MZ ? Z + (s-NX)*DD : Xt + (s-NX-MZ)*DD);
  float xv = xin[h];
  xs[h] = xv; XS[s*DD + h] = xv;
  // stage W2 transposed: coalesced global float4 read, scalar LDS stores
  {
    const float4* W2_4 = (const float4*)W2;
    #pragma unroll 4
    for (int it = 0; it < 32; ++it) {
      int f = it*128 + h;          // 0..4095
      int r = f >> 5;              // W2 row
      int q = f & 31;              // col/4
      float4 v = W2_4[f];
      w2t[(4*q+0)*129 + r] = v.x;
      w2t[(4*q+1)*129 + r] = v.y;
      w2t[(4*q+2)*129 + r] = v.z;
      w2t[(4*q+3)*129 + r] = v.w;
    }
  }
  __syncthreads();
  float acc = b1[h];
  #pragma unroll 8
  for (int d0 = 0; d0 < DD; ++d0) acc += xs[d0] * W1[d0*H + h];   // coalesced over h
  float a1 = tanhf(acc);
  a1s[h] = a1; A1[s*H + h] = a1;
  __syncthreads();
  acc = b2[h];
  #pragma unroll 8
  for (int d0 = 0; d0 < H; ++d0) acc += a1s[d0] * w2t[h*129 + d0];  // W2[d0][h], conflict-free
  float a2 = tanhf(acc);
  A2[s*H + h] = a2;
  float t2 = 1.0f - a2*a2;
  float g2v[CC];
  #pragma unroll
  for (int c = 0; c < CC; ++c) {
    g2v[c] = W3[h*CC + c] * t2;
    g2s[c*H + h] = g2v[c];
    G2[(s*CC + c)*H + h] = g2v[c];
  }
  __syncthreads();
  float t1 = 1.0f - a1*a1;
  float accs[CC];
  #pragma unroll
  for (int c = 0; c < CC; ++c) accs[c] = 0.0f;
  #pragma unroll 4
  for (int k = 0; k < H; ++k) {
    float w = w2t[k*129 + h];      // W2[h][k], conflict-free; g2s broadcast
    #pragma unroll
    for (int c = 0; c < CC; ++c) accs[c] += w * g2s[c*H + k];
  }
  #pragma unroll
  for (int c = 0; c < CC; ++c) G1[(s*CC + c)*H + h] = t1 * accs[c];
  // ---- fused Kxx_diag for test samples: single-barrier WRED ----
  if (s >= NX + MZ) {
    int t = s - NX - MZ;
    WRED(xv*xv, 0) WRED(a1*a1, 1) WRED(a2*a2, 2)
    #pragma unroll
    for (int c = 0; c < CC; ++c) {
      float g1v = t1 * accs[c];
      WRED(g1v*g1v, 3+2*c)
      WRED(g2v[c]*g2v[c], 4+2*c)
    }
    __syncthreads();
    if (h < CC) {
      int c = h;
      float nx  = partG[0] + partG[1];
      float na1 = partG[2] + partG[3];
      float na2 = partG[4] + partG[5];
      float n1 = partG[(3+2*c)*2] + partG[(3+2*c)*2+1];
      float n2 = partG[(4+2*c)*2] + partG[(4+2*c)*2+1];
      out[TN*CC + t*CC + c] = SCALE * ((1.0f+nx)*n1 + (1.0f+na1)*n2 + (1.0f+na2));
    }
  }
}

// Class-independent base dot products: 1+x.x', 1+a1.a1', 1+a2.a2'
__global__ __launch_bounds__(256) void k_base(const float* __restrict__ XS,
    const float* __restrict__ A1, const float* __restrict__ A2, float* __restrict__ Base)
{
  int set = blockIdx.z;
  int colsN = (set == 0) ? NX : MZ;
  if ((int)blockIdx.x * 16 >= colsN) return;
  int rowOff = (set == 2) ? NX+MZ : NX;
  int colOff = (set == 0) ? 0 : NX;
  unsigned baseOff = (set == 0) ? BASE_ZX : (set == 1 ? BASE_ZZ : BASE_TZ);
  __shared__ float rx[16*132], r1[16*132], r2[16*132], cxs[16*132], c1s[16*132], c2s[16*132];
  int tid = threadIdx.x, m0 = blockIdx.y*16, n0 = blockIdx.x*16;
  for (int idx = tid; idx < 16*128; idx += 256) {
    int r = idx >> 7, hh = idx & 127;
    int sr = rowOff + m0 + r, sc = colOff + n0 + r;
    rx [r*132+hh] = XS[sr*DD+hh]; r1[r*132+hh] = A1[sr*H+hh]; r2[r*132+hh] = A2[sr*H+hh];
    cxs[r*132+hh] = XS[sc*DD+hh]; c1s[r*132+hh] = A1[sc*H+hh]; c2s[r*132+hh] = A2[sc*H+hh];
  }
  __syncthreads();
  int ty = tid >> 4, tx = tid & 15;
  const float4* pa = (const float4*)(rx  + ty*132);
  const float4* pb = (const float4*)(cxs + tx*132);
  const float4* pc = (const float4*)(r1  + ty*132);
  const float4* pd = (const float4*)(c1s + tx*132);
  const float4* pe = (const float4*)(r2  + ty*132);
  const float4* pf = (const float4*)(c2s + tx*132);
  float d0 = 0, d1 = 0, d2 = 0;
  #pragma unroll 8
  for (int q = 0; q < 32; ++q) {
    float4 a = pa[q], b = pb[q]; d0 += a.x*b.x + a.y*b.y + a.z*b.z + a.w*b.w;
    float4 c = pc[q], d = pd[q]; d1 += c.x*d.x + c.y*d.y + c.z*d.z + c.w*d.w;
    float4 e = pe[q], f = pf[q]; d2 += e.x*f.x + e.y*f.y + e.z*f.z + e.w*f.w;
  }
  int m = m0 + ty, n = n0 + tx;
  float* Bp = Base + baseOff;
  int area = 128 * colsN;
  Bp[0*area + m*colsN + n] = 1.0f + d0;
  Bp[1*area + m*colsN + n] = 1.0f + d1;
  Bp[2*area + m*colsN + n] = 1.0f + d2;
}

// Per-class NTK gram: K = SCALE*(B0*(g1.g1') + B1*(g2.g2') + B2)
// set==0 additionally folds LamU[c][m] += sum_n Kzx[m][n]*Y[n][c] via shuffles+atomics.
__global__ __launch_bounds__(256) void k_gram(const float* __restrict__ G1, const float* __restrict__ G2,
    const float* __restrict__ Base, const float* __restrict__ Y,
    float* __restrict__ Kzx, float* __restrict__ Kzz, float* __restrict__ Kxz,
    float* __restrict__ LamU)
{
  int z = blockIdx.z, set = z / CC, c = z % CC;
  int colsN = (set == 0) ? NX : MZ;
  if ((int)blockIdx.x * 16 >= colsN) return;
  int rowOff = (set == 2) ? NX+MZ : NX;
  int colOff = (set == 0) ? 0 : NX;
  unsigned baseOff = (set == 0) ? BASE_ZX : (set == 1 ? BASE_ZZ : BASE_TZ);
  float* outp = (set == 0) ? Kzx + c*MZ*NX : (set == 1 ? Kzz + c*MZ*MZ : Kxz + c*TN*MZ);
  __shared__ float g1r[16*132], g2r[16*132], g1c[16*132], g2c[16*132];
  int tid = threadIdx.x, m0 = blockIdx.y*16, n0 = blockIdx.x*16;
  for (int idx = tid; idx < 2048; idx += 256) {
    int r = idx >> 7, hh = idx & 127;
    int sr = rowOff + m0 + r, sc = colOff + n0 + r;
    g1r[r*132+hh] = G1[(sr*CC + c)*H + hh]; g2r[r*132+hh] = G2[(sr*CC + c)*H + hh];
    g1c[r*132+hh] = G1[(sc*CC + c)*H + hh]; g2c[r*132+hh] = G2[(sc*CC + c)*H + hh];
  }
  __syncthreads();
  int ty = tid >> 4, tx = tid & 15;
  const float4* p1 = (const float4*)(g1r + ty*132);
  const float4* p2 = (const float4*)(g1c + tx*132);
  const float4* p3 = (const float4*)(g2r + ty*132);
  const float4* p4 = (const float4*)(g2c + tx*132);
  float dg1 = 0, dg2 = 0;
  #pragma unroll 8
  for (int q = 0; q < 32; ++q) {
    float4 a = p1[q], b = p2[q]; dg1 += a.x*b.x + a.y*b.y + a.z*b.z + a.w*b.w;
    float4 e = p3[q], f = p4[q]; dg2 += e.x*f.x + e.y*f.y + e.z*f.z + e.w*f.w;
  }
  int m = m0 + ty, n = n0 + tx;
  const float* Bp = Base + baseOff;
  int area = 128 * colsN;
  float b0 = Bp[m*colsN + n], b1v = Bp[area + m*colsN + n], b2v = Bp[2*area + m*colsN + n];
  float val = SCALE * (b0*dg1 + b1v*dg2 + b2v);
  outp[m*colsN + n] = val;
  if (set == 0) {
    float lam = val * Y[n*CC + c] * INV_S2;
    lam += __shfl_xor(lam, 1, 64); lam += __shfl_xor(lam, 2, 64);
    lam += __shfl_xor(lam, 4, 64); lam += __shfl_xor(lam, 8, 64);
    if (tx == 0) atomicAdd(&LamU[c*MZ + m], lam);
  }
}

// KzzB = Kzz + Kzx Kzx^T + 2*JIT*I ; Kzzj = Kzz + JIT*I  (single-barrier)
__global__ __launch_bounds__(256) void k_kzzb(const float* __restrict__ Kzx, const float* __restrict__ Kzz,
    float* __restrict__ Kzzj, float* __restrict__ KzzB)
{
  int c = blockIdx.z, m0 = blockIdx.y*16, k0 = blockIdx.x*16;
  int tid = threadIdx.x, ty = tid >> 4, tx = tid & 15;
  __shared__ float Am[16*260], Ak[16*260];
  const float* Kc = Kzx + c*MZ*NX;
  const float4* src_m = (const float4*)(Kc + m0*NX);
  const float4* src_k = (const float4*)(Kc + k0*NX);
  float4* Am4 = (float4*)Am;   // stride 65 float4 per row
  float4* Ak4 = (float4*)Ak;
  for (int idx = tid; idx < 16*64; idx += 256) {
    int r = idx >> 6, q = idx & 63;
    Am4[r*65 + q] = src_m[r*64 + q];
    Ak4[r*65 + q] = src_k[r*64 + q];
  }
  __syncthreads();
  const float4* am = (const float4*)(Am + ty*260);
  const float4* ak = (const float4*)(Ak + tx*260);
  float acc = 0;
  #pragma unroll 8
  for (int q = 0; q < 64; ++q) {
    float4 a = am[q], b = ak[q];
    acc += a.x*b.x + a.y*b.y + a.z*b.z + a.w*b.w;
  }
  int m = m0+ty, k = k0+tx, idx = c*MZ*MZ + m*MZ + k;
  float kzz = Kzz[idx];
  float dia = (m == k) ? 1.0f : 0.0f;
  Kzzj[idx] = kzz + dia*JIT;
  KzzB[idx] = kzz + acc*INV_S2 + dia*2.0f*JIT;
}

// Blocked (rank-4) Cholesky + folded ylam forward-subst, float4-vectorized
// triangular trailing update. Emits strictly-lower Lc, invd, ylam (which==1).
__global__ __launch_bounds__(512) void k_chol(const float* __restrict__ Kzzj, const float* __restrict__ KzzB,
    float* __restrict__ Lc, float* __restrict__ invd,
    const float* __restrict__ LamU, float* __restrict__ ylam)
{
  int which = blockIdx.x & 1, c = blockIdx.x >> 1;
  const float* Ain = (which ? KzzB : Kzzj) + c*MZ*MZ;
  float* LcB = Lc + (size_t)(which*CC + c)*MZ*MZ;
  float* invB = invd + (which*CC + c)*MZ;
  __shared__ float As[MZ*MZ];
  __shared__ float4 pan[MZ];
  __shared__ float bs[MZ];
  __shared__ float ys[MZ];
  int tid = threadIdx.x;
  int rg = tid & 31, kp = tid >> 5;
  float4* As4 = (float4*)As;
  {
    float4* d4 = (float4*)As; const float4* s4 = (const float4*)Ain;
    #pragma unroll
    for (int r = 0; r < 8; ++r) d4[tid + 512*r] = s4[tid + 512*r];
  }
  if (tid < MZ) bs[tid] = which ? LamU[c*MZ + tid] : 0.0f;
  __syncthreads();
  for (int jb = 0; jb < 32; ++jb) {
    int j = jb*4;
    if (tid < MZ) {
      int i = tid;
      float r0 = As[(j+0)*MZ + i], r1 = As[(j+1)*MZ + i], r2 = As[(j+2)*MZ + i], r3 = As[(j+3)*MZ + i];
      float a00 = As[j*MZ+j];
      float a10 = As[j*MZ+j+1], a20 = As[j*MZ+j+2], a30 = As[j*MZ+j+3];
      float a11 = As[(j+1)*MZ+j+1], a21 = As[(j+1)*MZ+j+2], a31 = As[(j+1)*MZ+j+3];
      float a22 = As[(j+2)*MZ+j+2], a32 = As[(j+2)*MZ+j+3];
      float a33 = As[(j+3)*MZ+j+3];
      float bj0 = bs[j], bj1 = bs[j+1], bj2 = bs[j+2], bj3 = bs[j+3];
      float id0 = rsqrtf(a00);
      float l10 = a10*id0, l20 = a20*id0, l30 = a30*id0;
      float id1 = rsqrtf(a11 - l10*l10);
      float l21 = (a21 - l20*l10)*id1, l31 = (a31 - l30*l10)*id1;
      float id2 = rsqrtf(a22 - l20*l20 - l21*l21);
      float l32 = (a32 - l30*l20 - l31*l21)*id2;
      float id3 = rsqrtf(a33 - l30*l30 - l31*l31 - l32*l32);
      float c0 = r0*id0;
      float c1 = (r1 - c0*l10)*id1;
      float c2 = (r2 - c0*l20 - c1*l21)*id2;
      float c3 = (r3 - c0*l30 - c1*l31 - c2*l32)*id3;
      float y0 = bj0*id0;
      float y1 = (bj1 - l10*y0)*id1;
      float y2 = (bj2 - l20*y0 - l21*y1)*id2;
      float y3 = (bj3 - l30*y0 - l31*y1 - l32*y2)*id3;
      pan[i] = make_float4(c0, c1, c2, c3);
      LcB[(j+0)*MZ + i] = (i > j+0) ? c0 : 0.0f;
      LcB[(j+1)*MZ + i] = (i > j+1) ? c1 : 0.0f;
      LcB[(j+2)*MZ + i] = (i > j+2) ? c2 : 0.0f;
      LcB[(j+3)*MZ + i] = (i > j+3) ? c3 : 0.0f;
      if (i == j) {
        invB[j] = id0; invB[j+1] = id1; invB[j+2] = id2; invB[j+3] = id3;
        ys[j] = y0; ys[j+1] = y1; ys[j+2] = y2; ys[j+3] = y3;
      }
      if (i >= j+4) bs[i] -= c0*y0 + c1*y1 + c2*y2 + c3*y3;
    }
    __syncthreads();
    float4 p0 = pan[4*rg+0], p1 = pan[4*rg+1], p2 = pan[4*rg+2], p3 = pan[4*rg+3];
    int kstart = (j + 4) + ((kp - (j + 4)) & 15);
    int kend = 4*rg + 3;
    for (int k = kstart; k <= kend; k += 16) {
      float4 ck = pan[k];
      float4 a4 = As4[k*32 + rg];
      a4.x -= p0.x*ck.x + p0.y*ck.y + p0.z*ck.z + p0.w*ck.w;
      a4.y -= p1.x*ck.x + p1.y*ck.y + p1.z*ck.z + p1.w*ck.w;
      a4.z -= p2.x*ck.x + p2.y*ck.y + p2.z*ck.z + p2.w*ck.w;
      a4.w -= p3.x*ck.x + p3.y*ck.y + p3.z*ck.z + p3.w*ck.w;
      As4[k*32 + rg] = a4;
    }
    __syncthreads();
  }
  if (which && tid < MZ) ylam[c*MZ + tid] = ys[tid];
}

// Forward substitution L W = Kzxt, wave-distributed columns; finalizes output
// (lane 0: atomicAdd ±sum(W^2) onto Kxxd base; which==1 writes f_mean).
__device__ __forceinline__ float rdlane(float v, int lane) {
  return __int_as_float(__builtin_amdgcn_readlane(__float_as_int(v), lane));
}

__global__ __launch_bounds__(512) void k_solve(const float* __restrict__ Lc,
    const float* __restrict__ invd, const float* __restrict__ ylam,
    const float* __restrict__ Kxz, float* __restrict__ out)
{
  int quarter = blockIdx.x & 3;
  int which   = (blockIdx.x >> 2) & 1;
  int c       = blockIdx.x >> 3;
  const float2* LcB2 = (const float2*)(Lc + (size_t)(which*CC + c)*MZ*MZ);
  const float2* invB2 = (const float2*)(invd + (which*CC + c)*MZ);
  const float2* ylB2  = (const float2*)(ylam + c*MZ);
  int tid = threadIdx.x, l = tid & 63, wv = tid >> 6;
  __shared__ float2 Ls[MZ*64];
  #pragma unroll
  for (int r = 0; r < 16; ++r) Ls[tid + 512*r] = LcB2[tid + 512*r];
  float2 iv = invB2[l];
  float2 yl = ylB2[l];
  int col0 = quarter*32 + wv*4;
  const float* K0 = Kxz + (size_t)c*TN*MZ;
  float2 b0 = *(const float2*)(K0 + (size_t)(col0+0)*MZ + 2*l);
  float2 b1 = *(const float2*)(K0 + (size_t)(col0+1)*MZ + 2*l);
  float2 b2 = *(const float2*)(K0 + (size_t)(col0+2)*MZ + 2*l);
  float2 b3 = *(const float2*)(K0 + (size_t)(col0+3)*MZ + 2*l);
  __syncthreads();
  #pragma unroll
  for (int j = 0; j < MZ; ++j) {
    const int owner = j >> 1;
    float2 Lj = Ls[j*64 + l];
    float y0, y1, y2, y3;
    if ((j & 1) == 0) {
      y0 = rdlane(b0.x * iv.x, owner);
      y1 = rdlane(b1.x * iv.x, owner);
      y2 = rdlane(b2.x * iv.x, owner);
      y3 = rdlane(b3.x * iv.x, owner);
    } else {
      y0 = rdlane(b0.y * iv.y, owner);
      y1 = rdlane(b1.y * iv.y, owner);
      y2 = rdlane(b2.y * iv.y, owner);
      y3 = rdlane(b3.y * iv.y, owner);
    }
    b0.x -= Lj.x * y0; b0.y -= Lj.y * y0;
    b1.x -= Lj.x * y1; b1.y -= Lj.y * y1;
    b2.x -= Lj.x * y2; b2.y -= Lj.y * y2;
    b3.x -= Lj.x * y3; b3.y -= Lj.y * y3;
    if (l == owner) {
      if ((j & 1) == 0) { b0.x = y0; b1.x = y1; b2.x = y2; b3.x = y3; }
      else              { b0.y = y0; b1.y = y1; b2.y = y2; b3.y = y3; }
    }
  }
  float sq0 = b0.x*b0.x + b0.y*b0.y, fm0 = b0.x*yl.x + b0.y*yl.y;
  float sq1 = b1.x*b1.x + b1.y*b1.y, fm1 = b1.x*yl.x + b1.y*yl.y;
  float sq2 = b2.x*b2.x + b2.y*b2.y, fm2 = b2.x*yl.x + b2.y*yl.y;
  float sq3 = b3.x*b3.x + b3.y*b3.y, fm3 = b3.x*yl.x + b3.y*yl.y;
  #pragma unroll
  for (int off = 32; off > 0; off >>= 1) {
    sq0 += __shfl_xor(sq0, off, 64); fm0 += __shfl_xor(fm0, off, 64);
    sq1 += __shfl_xor(sq1, off, 64); fm1 += __shfl_xor(fm1, off, 64);
    sq2 += __shfl_xor(sq2, off, 64); fm2 += __shfl_xor(fm2, off, 64);
    sq3 += __shfl_xor(sq3, off, 64); fm3 += __shfl_xor(fm3, off, 64);
  }
  if (l == 0) {
    float sgn = which ? 1.0f : -1.0f;
    float* var = out + TN*CC;
    atomicAdd(&var[(col0+0)*CC + c], sgn*sq0);
    atomicAdd(&var[(col0+1)*CC + c], sgn*sq1);
    atomicAdd(&var[(col0+2)*CC + c], sgn*sq2);
    atomicAdd(&var[(col0+3)*CC + c], sgn*sq3);
    if (which) {
      out[(col0+0)*CC + c] = fm0;
      out[(col0+1)*CC + c] = fm1;
      out[(col0+2)*CC + c] = fm2;
      out[(col0+3)*CC + c] = fm3;
    }
  }
}

extern "C" void kernel_launch(void* const* d_in, const int* in_sizes, int n_in,
                              void* d_out, int out_size, void* d_ws, size_t ws_size,
                              hipStream_t stream) {
  (void)in_sizes; (void)n_in; (void)out_size; (void)ws_size;
  const float* X  = (const float*)d_in[0];
  const float* Y  = (const float*)d_in[1];
  const float* Z  = (const float*)d_in[2];
  const float* Xt = (const float*)d_in[3];
  const float* W1 = (const float*)d_in[4];
  const float* b1 = (const float*)d_in[5];
  const float* W2 = (const float*)d_in[6];
  const float* b2 = (const float*)d_in[7];
  const float* W3 = (const float*)d_in[8];
  float* ws  = (float*)d_ws;
  float* out = (float*)d_out;

  float* XS   = ws + OFF_XS;
  float* A1   = ws + OFF_A1;
  float* A2   = ws + OFF_A2;
  float* G1   = ws + OFF_G1;
  float* G2   = ws + OFF_G2;
  float* Base = ws + OFF_BASE;
  float* Kzx  = ws + OFF_KZX;
  float* Kzz  = ws + OFF_KZZ;
  float* Kxz  = ws + OFF_KXZ;
  float* Kzzj = ws + OFF_KZZJ;
  float* KzzB = ws + OFF_KZZB;
  float* LamU = ws + OFF_LAMU;
  float* Lc   = ws + OFF_LC;
  float* invd = ws + OFF_INVD;
  float* ylam = ws + OFF_YLAM;

  k_features<<<S_TOT, 128, 0, stream>>>(X, Z, Xt, W1, b1, W2, b2, W3, XS, A1, A2, G1, G2, LamU, out);
  k_base<<<dim3(16, 8, 3), 256, 0, stream>>>(XS, A1, A2, Base);
  k_gram<<<dim3(16, 8, 3*CC), 256, 0, stream>>>(G1, G2, Base, Y, Kzx, Kzz, Kxz, LamU);
  k_kzzb<<<dim3(8, 8, CC), 256, 0, stream>>>(Kzx, Kzz, Kzzj, KzzB);
  k_chol<<<2*CC, 512, 0, stream>>>(Kzzj, KzzB, Lc, invd, LamU, ylam);
  k_solve<<<8*CC, 512, 0, stream>>>(Lc, invd, ylam, Kxz, out);
}

// Round 17
// 120.893 us; speedup vs baseline: 1.0006x; 1.0006x over previous
//
#include <hip/hip_runtime.h>

// NTK-SVGP forward: D=H=128, C=10, N=256, M=128, T=128, sigma2=1, delta=1
#define H 128
#define DD 128
#define CC 10
#define NX 256
#define MZ 128
#define TN 128
#define S_TOT 512
#define SCALE (1.0f/256.0f)
#define JIT 1e-3f
#define INV_S2 1.0f

// ---------------- ws layout (float offsets) ----------------
#define OFF_XS    0u
#define OFF_A1    (OFF_XS   + S_TOT*DD)
#define OFF_A2    (OFF_A1   + S_TOT*H)
#define OFF_G1    (OFF_A2   + S_TOT*H)
#define OFF_G2    (OFF_G1   + S_TOT*CC*H)
#define OFF_BASE  (OFF_G2   + S_TOT*CC*H)
#define BASE_ZX   0u
#define BASE_ZZ   (3u*MZ*NX)
#define BASE_TZ   (3u*MZ*NX + 3u*MZ*MZ)
#define OFF_KZX   (OFF_BASE + 3u*MZ*NX + 3u*MZ*MZ + 3u*TN*MZ)
#define OFF_KZZ   (OFF_KZX  + CC*MZ*NX)
#define OFF_KXZ   (OFF_KZZ  + CC*MZ*MZ)
#define OFF_KZZJ  (OFF_KXZ  + CC*TN*MZ)
#define OFF_KZZB  (OFF_KZZJ + CC*MZ*MZ)
#define OFF_LAMU  (OFF_KZZB + CC*MZ*MZ)
#define OFF_LC    (OFF_LAMU + CC*MZ)
#define OFF_INVD  (OFF_LC   + 2u*CC*MZ*MZ)
#define OFF_YLAM  (OFF_INVD + 2u*CC*MZ)

// wave-reduce val over 64 lanes; lane0 of each wave writes partG[qi*2 + waveIdx]
#define WRED(val, qi) { float v_ = (val);                                     \
  v_ += __shfl_down(v_,32,64); v_ += __shfl_down(v_,16,64);                   \
  v_ += __shfl_down(v_, 8,64); v_ += __shfl_down(v_, 4,64);                   \
  v_ += __shfl_down(v_, 2,64); v_ += __shfl_down(v_, 1,64);                   \
  if ((h & 63) == 0) partG[(qi)*2 + (h>>6)] = v_; }

// Per-sample forward + backprop features. One block per sample, 128 threads.
// - W2 staged to LDS TRANSPOSED once per block (pad 129 -> conflict-free):
//   both the layer-2 matvec and the G1 backprop loop read LDS, eliminating
//   the 512B-stride divergent global reads that made R14's version 42us.
// - Test-sample blocks emit Kxx_diag into out's f_var half via the
//   single-barrier WRED reduction (verified in R13's mega P1).
// - Block s==0 zeroes LamU (k_gram, a later launch, atomicAdds into it).
__global__ __launch_bounds__(128) void k_features(
    const float* __restrict__ X, const float* __restrict__ Z, const float* __restrict__ Xt,
    const float* __restrict__ W1, const float* __restrict__ b1,
    const float* __restrict__ W2, const float* __restrict__ b2,
    const float* __restrict__ W3,
    float* __restrict__ XS, float* __restrict__ A1, float* __restrict__ A2,
    float* __restrict__ G1, float* __restrict__ G2, float* __restrict__ LamU,
    float* __restrict__ out)
{
  int s = blockIdx.x, h = threadIdx.x;
  __shared__ float xs[DD], a1s[H], g2s[CC*H];
  __shared__ float w2t[H*129];   // w2t[c*129 + r] = W2[r][c]
  __shared__ float partG[46];
  if (s == 0) {
    #pragma unroll
    for (int c = 0; c < CC; ++c) LamU[c*MZ + h] = 0.0f;
  }
  const float* xin = (s < NX) ? X + s*DD : (s < NX+MZ ? Z + (s-NX)*DD : Xt + (s-NX-MZ)*DD);
  float xv = xin[h];
  xs[h] = xv; XS[s*DD + h] = xv;
  // stage W2 transposed: coalesced global float4 read, scalar LDS stores
  {
    const float4* W2_4 = (const float4*)W2;
    #pragma unroll 4
    for (int it = 0; it < 32; ++it) {
      int f = it*128 + h;          // 0..4095
      int r = f >> 5;              // W2 row
      int q = f & 31;              // col/4
      float4 v = W2_4[f];
      w2t[(4*q+0)*129 + r] = v.x;
      w2t[(4*q+1)*129 + r] = v.y;
      w2t[(4*q+2)*129 + r] = v.z;
      w2t[(4*q+3)*129 + r] = v.w;
    }
  }
  __syncthreads();
  float acc = b1[h];
  #pragma unroll 8
  for (int d0 = 0; d0 < DD; ++d0) acc += xs[d0] * W1[d0*H + h];   // coalesced over h
  float a1 = tanhf(acc);
  a1s[h] = a1; A1[s*H + h] = a1;
  __syncthreads();
  acc = b2[h];
  #pragma unroll 8
  for (int d0 = 0; d0 < H; ++d0) acc += a1s[d0] * w2t[h*129 + d0];  // W2[d0][h], conflict-free
  float a2 = tanhf(acc);
  A2[s*H + h] = a2;
  float t2 = 1.0f - a2*a2;
  float g2v[CC];
  #pragma unroll
  for (int c = 0; c < CC; ++c) {
    g2v[c] = W3[h*CC + c] * t2;
    g2s[c*H + h] = g2v[c];
    G2[(s*CC + c)*H + h] = g2v[c];
  }
  __syncthreads();
  float t1 = 1.0f - a1*a1;
  float accs[CC];
  #pragma unroll
  for (int c = 0; c < CC; ++c) accs[c] = 0.0f;
  #pragma unroll 4
  for (int k = 0; k < H; ++k) {
    float w = w2t[k*129 + h];      // W2[h][k], conflict-free; g2s broadcast
    #pragma unroll
    for (int c = 0; c < CC; ++c) accs[c] += w * g2s[c*H + k];
  }
  #pragma unroll
  for (int c = 0; c < CC; ++c) G1[(s*CC + c)*H + h] = t1 * accs[c];
  // ---- fused Kxx_diag for test samples: single-barrier WRED ----
  if (s >= NX + MZ) {
    int t = s - NX - MZ;
    WRED(xv*xv, 0) WRED(a1*a1, 1) WRED(a2*a2, 2)
    #pragma unroll
    for (int c = 0; c < CC; ++c) {
      float g1v = t1 * accs[c];
      WRED(g1v*g1v, 3+2*c)
      WRED(g2v[c]*g2v[c], 4+2*c)
    }
    __syncthreads();
    if (h < CC) {
      int c = h;
      float nx  = partG[0] + partG[1];
      float na1 = partG[2] + partG[3];
      float na2 = partG[4] + partG[5];
      float n1 = partG[(3+2*c)*2] + partG[(3+2*c)*2+1];
      float n2 = partG[(4+2*c)*2] + partG[(4+2*c)*2+1];
      out[TN*CC + t*CC + c] = SCALE * ((1.0f+nx)*n1 + (1.0f+na1)*n2 + (1.0f+na2));
    }
  }
}

// Class-independent base dot products: 1+x.x', 1+a1.a1', 1+a2.a2'
__global__ __launch_bounds__(256) void k_base(const float* __restrict__ XS,
    const float* __restrict__ A1, const float* __restrict__ A2, float* __restrict__ Base)
{
  int set = blockIdx.z;
  int colsN = (set == 0) ? NX : MZ;
  if ((int)blockIdx.x * 16 >= colsN) return;
  int rowOff = (set == 2) ? NX+MZ : NX;
  int colOff = (set == 0) ? 0 : NX;
  unsigned baseOff = (set == 0) ? BASE_ZX : (set == 1 ? BASE_ZZ : BASE_TZ);
  __shared__ float rx[16*132], r1[16*132], r2[16*132], cxs[16*132], c1s[16*132], c2s[16*132];
  int tid = threadIdx.x, m0 = blockIdx.y*16, n0 = blockIdx.x*16;
  for (int idx = tid; idx < 16*128; idx += 256) {
    int r = idx >> 7, hh = idx & 127;
    int sr = rowOff + m0 + r, sc = colOff + n0 + r;
    rx [r*132+hh] = XS[sr*DD+hh]; r1[r*132+hh] = A1[sr*H+hh]; r2[r*132+hh] = A2[sr*H+hh];
    cxs[r*132+hh] = XS[sc*DD+hh]; c1s[r*132+hh] = A1[sc*H+hh]; c2s[r*132+hh] = A2[sc*H+hh];
  }
  __syncthreads();
  int ty = tid >> 4, tx = tid & 15;
  const float4* pa = (const float4*)(rx  + ty*132);
  const float4* pb = (const float4*)(cxs + tx*132);
  const float4* pc = (const float4*)(r1  + ty*132);
  const float4* pd = (const float4*)(c1s + tx*132);
  const float4* pe = (const float4*)(r2  + ty*132);
  const float4* pf = (const float4*)(c2s + tx*132);
  float d0 = 0, d1 = 0, d2 = 0;
  #pragma unroll 8
  for (int q = 0; q < 32; ++q) {
    float4 a = pa[q], b = pb[q]; d0 += a.x*b.x + a.y*b.y + a.z*b.z + a.w*b.w;
    float4 c = pc[q], d = pd[q]; d1 += c.x*d.x + c.y*d.y + c.z*d.z + c.w*d.w;
    float4 e = pe[q], f = pf[q]; d2 += e.x*f.x + e.y*f.y + e.z*f.z + e.w*f.w;
  }
  int m = m0 + ty, n = n0 + tx;
  float* Bp = Base + baseOff;
  int area = 128 * colsN;
  Bp[0*area + m*colsN + n] = 1.0f + d0;
  Bp[1*area + m*colsN + n] = 1.0f + d1;
  Bp[2*area + m*colsN + n] = 1.0f + d2;
}

// Per-class NTK gram: K = SCALE*(B0*(g1.g1') + B1*(g2.g2') + B2)
// set==0 additionally folds LamU[c][m] += sum_n Kzx[m][n]*Y[n][c] via shuffles+atomics.
__global__ __launch_bounds__(256) void k_gram(const float* __restrict__ G1, const float* __restrict__ G2,
    const float* __restrict__ Base, const float* __restrict__ Y,
    float* __restrict__ Kzx, float* __restrict__ Kzz, float* __restrict__ Kxz,
    float* __restrict__ LamU)
{
  int z = blockIdx.z, set = z / CC, c = z % CC;
  int colsN = (set == 0) ? NX : MZ;
  if ((int)blockIdx.x * 16 >= colsN) return;
  int rowOff = (set == 2) ? NX+MZ : NX;
  int colOff = (set == 0) ? 0 : NX;
  unsigned baseOff = (set == 0) ? BASE_ZX : (set == 1 ? BASE_ZZ : BASE_TZ);
  float* outp = (set == 0) ? Kzx + c*MZ*NX : (set == 1 ? Kzz + c*MZ*MZ : Kxz + c*TN*MZ);
  __shared__ float g1r[16*132], g2r[16*132], g1c[16*132], g2c[16*132];
  int tid = threadIdx.x, m0 = blockIdx.y*16, n0 = blockIdx.x*16;
  for (int idx = tid; idx < 2048; idx += 256) {
    int r = idx >> 7, hh = idx & 127;
    int sr = rowOff + m0 + r, sc = colOff + n0 + r;
    g1r[r*132+hh] = G1[(sr*CC + c)*H + hh]; g2r[r*132+hh] = G2[(sr*CC + c)*H + hh];
    g1c[r*132+hh] = G1[(sc*CC + c)*H + hh]; g2c[r*132+hh] = G2[(sc*CC + c)*H + hh];
  }
  __syncthreads();
  int ty = tid >> 4, tx = tid & 15;
  const float4* p1 = (const float4*)(g1r + ty*132);
  const float4* p2 = (const float4*)(g1c + tx*132);
  const float4* p3 = (const float4*)(g2r + ty*132);
  const float4* p4 = (const float4*)(g2c + tx*132);
  float dg1 = 0, dg2 = 0;
  #pragma unroll 8
  for (int q = 0; q < 32; ++q) {
    float4 a = p1[q], b = p2[q]; dg1 += a.x*b.x + a.y*b.y + a.z*b.z + a.w*b.w;
    float4 e = p3[q], f = p4[q]; dg2 += e.x*f.x + e.y*f.y + e.z*f.z + e.w*f.w;
  }
  int m = m0 + ty, n = n0 + tx;
  const float* Bp = Base + baseOff;
  int area = 128 * colsN;
  float b0 = Bp[m*colsN + n], b1v = Bp[area + m*colsN + n], b2v = Bp[2*area + m*colsN + n];
  float val = SCALE * (b0*dg1 + b1v*dg2 + b2v);
  outp[m*colsN + n] = val;
  if (set == 0) {
    float lam = val * Y[n*CC + c] * INV_S2;
    lam += __shfl_xor(lam, 1, 64); lam += __shfl_xor(lam, 2, 64);
    lam += __shfl_xor(lam, 4, 64); lam += __shfl_xor(lam, 8, 64);
    if (tx == 0) atomicAdd(&LamU[c*MZ + m], lam);
  }
}

// KzzB = Kzz + Kzx Kzx^T + 2*JIT*I ; Kzzj = Kzz + JIT*I  (single-barrier)
__global__ __launch_bounds__(256) void k_kzzb(const float* __restrict__ Kzx, const float* __restrict__ Kzz,
    float* __restrict__ Kzzj, float* __restrict__ KzzB)
{
  int c = blockIdx.z, m0 = blockIdx.y*16, k0 = blockIdx.x*16;
  int tid = threadIdx.x, ty = tid >> 4, tx = tid & 15;
  __shared__ float Am[16*260], Ak[16*260];
  const float* Kc = Kzx + c*MZ*NX;
  const float4* src_m = (const float4*)(Kc + m0*NX);
  const float4* src_k = (const float4*)(Kc + k0*NX);
  float4* Am4 = (float4*)Am;   // stride 65 float4 per row
  float4* Ak4 = (float4*)Ak;
  for (int idx = tid; idx < 16*64; idx += 256) {
    int r = idx >> 6, q = idx & 63;
    Am4[r*65 + q] = src_m[r*64 + q];
    Ak4[r*65 + q] = src_k[r*64 + q];
  }
  __syncthreads();
  const float4* am = (const float4*)(Am + ty*260);
  const float4* ak = (const float4*)(Ak + tx*260);
  float acc = 0;
  #pragma unroll 8
  for (int q = 0; q < 64; ++q) {
    float4 a = am[q], b = ak[q];
    acc += a.x*b.x + a.y*b.y + a.z*b.z + a.w*b.w;
  }
  int m = m0+ty, k = k0+tx, idx = c*MZ*MZ + m*MZ + k;
  float kzz = Kzz[idx];
  float dia = (m == k) ? 1.0f : 0.0f;
  Kzzj[idx] = kzz + dia*JIT;
  KzzB[idx] = kzz + acc*INV_S2 + dia*2.0f*JIT;
}

// Blocked (rank-4) Cholesky + folded ylam forward-subst, float4-vectorized
// triangular trailing update. Emits strictly-lower Lc, invd, ylam (which==1).
__global__ __launch_bounds__(512) void k_chol(const float* __restrict__ Kzzj, const float* __restrict__ KzzB,
    float* __restrict__ Lc, float* __restrict__ invd,
    const float* __restrict__ LamU, float* __restrict__ ylam)
{
  int which = blockIdx.x & 1, c = blockIdx.x >> 1;
  const float* Ain = (which ? KzzB : Kzzj) + c*MZ*MZ;
  float* LcB = Lc + (size_t)(which*CC + c)*MZ*MZ;
  float* invB = invd + (which*CC + c)*MZ;
  __shared__ float As[MZ*MZ];
  __shared__ float4 pan[MZ];
  __shared__ float bs[MZ];
  __shared__ float ys[MZ];
  int tid = threadIdx.x;
  int rg = tid & 31, kp = tid >> 5;
  float4* As4 = (float4*)As;
  {
    float4* d4 = (float4*)As; const float4* s4 = (const float4*)Ain;
    #pragma unroll
    for (int r = 0; r < 8; ++r) d4[tid + 512*r] = s4[tid + 512*r];
  }
  if (tid < MZ) bs[tid] = which ? LamU[c*MZ + tid] : 0.0f;
  __syncthreads();
  for (int jb = 0; jb < 32; ++jb) {
    int j = jb*4;
    if (tid < MZ) {
      int i = tid;
      float r0 = As[(j+0)*MZ + i], r1 = As[(j+1)*MZ + i], r2 = As[(j+2)*MZ + i], r3 = As[(j+3)*MZ + i];
      float a00 = As[j*MZ+j];
      float a10 = As[j*MZ+j+1], a20 = As[j*MZ+j+2], a30 = As[j*MZ+j+3];
      float a11 = As[(j+1)*MZ+j+1], a21 = As[(j+1)*MZ+j+2], a31 = As[(j+1)*MZ+j+3];
      float a22 = As[(j+2)*MZ+j+2], a32 = As[(j+2)*MZ+j+3];
      float a33 = As[(j+3)*MZ+j+3];
      float bj0 = bs[j], bj1 = bs[j+1], bj2 = bs[j+2], bj3 = bs[j+3];
      float id0 = rsqrtf(a00);
      float l10 = a10*id0, l20 = a20*id0, l30 = a30*id0;
      float id1 = rsqrtf(a11 - l10*l10);
      float l21 = (a21 - l20*l10)*id1, l31 = (a31 - l30*l10)*id1;
      float id2 = rsqrtf(a22 - l20*l20 - l21*l21);
      float l32 = (a32 - l30*l20 - l31*l21)*id2;
      float id3 = rsqrtf(a33 - l30*l30 - l31*l31 - l32*l32);
      float c0 = r0*id0;
      float c1 = (r1 - c0*l10)*id1;
      float c2 = (r2 - c0*l20 - c1*l21)*id2;
      float c3 = (r3 - c0*l30 - c1*l31 - c2*l32)*id3;
      float y0 = bj0*id0;
      float y1 = (bj1 - l10*y0)*id1;
      float y2 = (bj2 - l20*y0 - l21*y1)*id2;
      float y3 = (bj3 - l30*y0 - l31*y1 - l32*y2)*id3;
      pan[i] = make_float4(c0, c1, c2, c3);
      LcB[(j+0)*MZ + i] = (i > j+0) ? c0 : 0.0f;
      LcB[(j+1)*MZ + i] = (i > j+1) ? c1 : 0.0f;
      LcB[(j+2)*MZ + i] = (i > j+2) ? c2 : 0.0f;
      LcB[(j+3)*MZ + i] = (i > j+3) ? c3 : 0.0f;
      if (i == j) {
        invB[j] = id0; invB[j+1] = id1; invB[j+2] = id2; invB[j+3] = id3;
        ys[j] = y0; ys[j+1] = y1; ys[j+2] = y2; ys[j+3] = y3;
      }
      if (i >= j+4) bs[i] -= c0*y0 + c1*y1 + c2*y2 + c3*y3;
    }
    __syncthreads();
    float4 p0 = pan[4*rg+0], p1 = pan[4*rg+1], p2 = pan[4*rg+2], p3 = pan[4*rg+3];
    int kstart = (j + 4) + ((kp - (j + 4)) & 15);
    int kend = 4*rg + 3;
    for (int k = kstart; k <= kend; k += 16) {
      float4 ck = pan[k];
      float4 a4 = As4[k*32 + rg];
      a4.x -= p0.x*ck.x + p0.y*ck.y + p0.z*ck.z + p0.w*ck.w;
      a4.y -= p1.x*ck.x + p1.y*ck.y + p1.z*ck.z + p1.w*ck.w;
      a4.z -= p2.x*ck.x + p2.y*ck.y + p2.z*ck.z + p2.w*ck.w;
      a4.w -= p3.x*ck.x + p3.y*ck.y + p3.z*ck.z + p3.w*ck.w;
      As4[k*32 + rg] = a4;
    }
    __syncthreads();
  }
  if (which && tid < MZ) ylam[c*MZ + tid] = ys[tid];
}

// Forward substitution L W = Kzxt, wave-distributed columns; finalizes output
// (lane 0: atomicAdd ±sum(W^2) onto Kxxd base; which==1 writes f_mean).
__device__ __forceinline__ float rdlane(float v, int lane) {
  return __int_as_float(__builtin_amdgcn_readlane(__float_as_int(v), lane));
}

__global__ __launch_bounds__(512) void k_solve(const float* __restrict__ Lc,
    const float* __restrict__ invd, const float* __restrict__ ylam,
    const float* __restrict__ Kxz, float* __restrict__ out)
{
  int quarter = blockIdx.x & 3;
  int which   = (blockIdx.x >> 2) & 1;
  int c       = blockIdx.x >> 3;
  const float2* LcB2 = (const float2*)(Lc + (size_t)(which*CC + c)*MZ*MZ);
  const float2* invB2 = (const float2*)(invd + (which*CC + c)*MZ);
  const float2* ylB2  = (const float2*)(ylam + c*MZ);
  int tid = threadIdx.x, l = tid & 63, wv = tid >> 6;
  __shared__ float2 Ls[MZ*64];
  #pragma unroll
  for (int r = 0; r < 16; ++r) Ls[tid + 512*r] = LcB2[tid + 512*r];
  float2 iv = invB2[l];
  float2 yl = ylB2[l];
  int col0 = quarter*32 + wv*4;
  const float* K0 = Kxz + (size_t)c*TN*MZ;
  float2 b0 = *(const float2*)(K0 + (size_t)(col0+0)*MZ + 2*l);
  float2 b1 = *(const float2*)(K0 + (size_t)(col0+1)*MZ + 2*l);
  float2 b2 = *(const float2*)(K0 + (size_t)(col0+2)*MZ + 2*l);
  float2 b3 = *(const float2*)(K0 + (size_t)(col0+3)*MZ + 2*l);
  __syncthreads();
  #pragma unroll
  for (int j = 0; j < MZ; ++j) {
    const int owner = j >> 1;
    float2 Lj = Ls[j*64 + l];
    float y0, y1, y2, y3;
    if ((j & 1) == 0) {
      y0 = rdlane(b0.x * iv.x, owner);
      y1 = rdlane(b1.x * iv.x, owner);
      y2 = rdlane(b2.x * iv.x, owner);
      y3 = rdlane(b3.x * iv.x, owner);
    } else {
      y0 = rdlane(b0.y * iv.y, owner);
      y1 = rdlane(b1.y * iv.y, owner);
      y2 = rdlane(b2.y * iv.y, owner);
      y3 = rdlane(b3.y * iv.y, owner);
    }
    b0.x -= Lj.x * y0; b0.y -= Lj.y * y0;
    b1.x -= Lj.x * y1; b1.y -= Lj.y * y1;
    b2.x -= Lj.x * y2; b2.y -= Lj.y * y2;
    b3.x -= Lj.x * y3; b3.y -= Lj.y * y3;
    if (l == owner) {
      if ((j & 1) == 0) { b0.x = y0; b1.x = y1; b2.x = y2; b3.x = y3; }
      else              { b0.y = y0; b1.y = y1; b2.y = y2; b3.y = y3; }
    }
  }
  float sq0 = b0.x*b0.x + b0.y*b0.y, fm0 = b0.x*yl.x + b0.y*yl.y;
  float sq1 = b1.x*b1.x + b1.y*b1.y, fm1 = b1.x*yl.x + b1.y*yl.y;
  float sq2 = b2.x*b2.x + b2.y*b2.y, fm2 = b2.x*yl.x + b2.y*yl.y;
  float sq3 = b3.x*b3.x + b3.y*b3.y, fm3 = b3.x*yl.x + b3.y*yl.y;
  #pragma unroll
  for (int off = 32; off > 0; off >>= 1) {
    sq0 += __shfl_xor(sq0, off, 64); fm0 += __shfl_xor(fm0, off, 64);
    sq1 += __shfl_xor(sq1, off, 64); fm1 += __shfl_xor(fm1, off, 64);
    sq2 += __shfl_xor(sq2, off, 64); fm2 += __shfl_xor(fm2, off, 64);
    sq3 += __shfl_xor(sq3, off, 64); fm3 += __shfl_xor(fm3, off, 64);
  }
  if (l == 0) {
    float sgn = which ? 1.0f : -1.0f;
    float* var = out + TN*CC;
    atomicAdd(&var[(col0+0)*CC + c], sgn*sq0);
    atomicAdd(&var[(col0+1)*CC + c], sgn*sq1);
    atomicAdd(&var[(col0+2)*CC + c], sgn*sq2);
    atomicAdd(&var[(col0+3)*CC + c], sgn*sq3);
    if (which) {
      out[(col0+0)*CC + c] = fm0;
      out[(col0+1)*CC + c] = fm1;
      out[(col0+2)*CC + c] = fm2;
      out[(col0+3)*CC + c] = fm3;
    }
  }
}

extern "C" void kernel_launch(void* const* d_in, const int* in_sizes, int n_in,
                              void* d_out, int out_size, void* d_ws, size_t ws_size,
                              hipStream_t stream) {
  (void)in_sizes; (void)n_in; (void)out_size; (void)ws_size;
  const float* X  = (const float*)d_in[0];
  const float* Y  = (const float*)d_in[1];
  const float* Z  = (const float*)d_in[2];
  const float* Xt = (const float*)d_in[3];
  const float* W1 = (const float*)d_in[4];
  const float* b1 = (const float*)d_in[5];
  const float* W2 = (const float*)d_in[6];
  const float* b2 = (const float*)d_in[7];
  const float* W3 = (const float*)d_in[8];
  float* ws  = (float*)d_ws;
  float* out = (float*)d_out;

  float* XS   = ws + OFF_XS;
  float* A1   = ws + OFF_A1;
  float* A2   = ws + OFF_A2;
  float* G1   = ws + OFF_G1;
  float* G2   = ws + OFF_G2;
  float* Base = ws + OFF_BASE;
  float* Kzx  = ws + OFF_KZX;
  float* Kzz  = ws + OFF_KZZ;
  float* Kxz  = ws + OFF_KXZ;
  float* Kzzj = ws + OFF_KZZJ;
  float* KzzB = ws + OFF_KZZB;
  float* LamU = ws + OFF_LAMU;
  float* Lc   = ws + OFF_LC;
  float* invd = ws + OFF_INVD;
  float* ylam = ws + OFF_YLAM;

  k_features<<<S_TOT, 128, 0, stream>>>(X, Z, Xt, W1, b1, W2, b2, W3, XS, A1, A2, G1, G2, LamU, out);
  k_base<<<dim3(16, 8, 3), 256, 0, stream>>>(XS, A1, A2, Base);
  k_gram<<<dim3(16, 8, 3*CC), 256, 0, stream>>>(G1, G2, Base, Y, Kzx, Kzz, Kxz, LamU);
  k_kzzb<<<dim3(8, 8, CC), 256, 0, stream>>>(Kzx, Kzz, Kzzj, KzzB);
  k_chol<<<2*CC, 512, 0, stream>>>(Kzzj, KzzB, Lc, invd, LamU, ylam);
  k_solve<<<8*CC, 512, 0, stream>>>(Lc, invd, ylam, Kxz, out);
}

// Round 18
// 116.941 us; speedup vs baseline: 1.0344x; 1.0338x over previous
//
#include <hip/hip_runtime.h>

// NTK-SVGP forward: D=H=128, C=10, N=256, M=128, T=128, sigma2=1, delta=1
#define H 128
#define DD 128
#define CC 10
#define NX 256
#define MZ 128
#define TN 128
#define S_TOT 512
#define SCALE (1.0f/256.0f)
#define JIT 1e-3f
#define INV_S2 1.0f

// ---------------- ws layout (float offsets) ----------------
#define OFF_XS    0u
#define OFF_A1    (OFF_XS   + S_TOT*DD)
#define OFF_A2    (OFF_A1   + S_TOT*H)
#define OFF_G1    (OFF_A2   + S_TOT*H)
#define OFF_G2    (OFF_G1   + S_TOT*CC*H)
#define OFF_BASE  (OFF_G2   + S_TOT*CC*H)
#define BASE_ZX   0u
#define BASE_ZZ   (3u*MZ*NX)
#define BASE_TZ   (3u*MZ*NX + 3u*MZ*MZ)
#define OFF_KZX   (OFF_BASE + 3u*MZ*NX + 3u*MZ*MZ + 3u*TN*MZ)
#define OFF_KZZ   (OFF_KZX  + CC*MZ*NX)
#define OFF_KXZ   (OFF_KZZ  + CC*MZ*MZ)
#define OFF_KZZJ  (OFF_KXZ  + CC*TN*MZ)
#define OFF_KZZB  (OFF_KZZJ + CC*MZ*MZ)
#define OFF_LAMU  (OFF_KZZB + CC*MZ*MZ)
#define OFF_LC    (OFF_LAMU + CC*MZ)
#define OFF_INVD  (OFF_LC   + 2u*CC*MZ*MZ)
#define OFF_YLAM  (OFF_INVD + 2u*CC*MZ)

// wave-reduce val over 64 lanes; lane0 of each wave writes partG[qi*2 + waveIdxInHalf]
#define WRED(val, qi) { float v_ = (val);                                     \
  v_ += __shfl_down(v_,32,64); v_ += __shfl_down(v_,16,64);                   \
  v_ += __shfl_down(v_, 8,64); v_ += __shfl_down(v_, 4,64);                   \
  v_ += __shfl_down(v_, 2,64); v_ += __shfl_down(v_, 1,64);                   \
  if ((h & 63) == 0) partG[(qi)*2 + (h>>6)] = v_; }

// Features: 2 samples per block (256 threads), W2 staged transposed to LDS
// once per block (pad 129 -> conflict-free). Test samples emit Kxx_diag into
// out's f_var half (single-barrier WRED). Block 0 (g==0 half) zeroes LamU.
__global__ __launch_bounds__(256) void k_features(
    const float* __restrict__ X, const float* __restrict__ Z, const float* __restrict__ Xt,
    const float* __restrict__ W1, const float* __restrict__ b1,
    const float* __restrict__ W2, const float* __restrict__ b2,
    const float* __restrict__ W3,
    float* __restrict__ XS, float* __restrict__ A1, float* __restrict__ A2,
    float* __restrict__ G1, float* __restrict__ G2, float* __restrict__ LamU,
    float* __restrict__ out)
{
  int b = blockIdx.x, tid = threadIdx.x;
  int g = tid >> 7, h = tid & 127;
  int s = 2*b + g;
  __shared__ float w2t[H*129];        // w2t[c*129 + r] = W2[r][c]
  __shared__ float xs[2][DD], a1s[2][H], g2s[2][CC*H];
  __shared__ float partGA[2][46];
  float* partG = partGA[g];
  if (b == 0 && tid < 128) {
    #pragma unroll
    for (int c = 0; c < CC; ++c) LamU[c*MZ + tid] = 0.0f;
  }
  const float* xin = (s < NX) ? X + s*DD : (s < NX+MZ ? Z + (s-NX)*DD : Xt + (s-NX-MZ)*DD);
  float xv = xin[h];
  xs[g][h] = xv; XS[s*DD + h] = xv;
  // stage W2 transposed: coalesced global float4 read, scalar LDS stores
  {
    const float4* W2_4 = (const float4*)W2;
    #pragma unroll 4
    for (int it = 0; it < 16; ++it) {
      int f = it*256 + tid;        // 0..4095
      int r = f >> 5;              // W2 row
      int q = f & 31;              // col/4
      float4 v = W2_4[f];
      w2t[(4*q+0)*129 + r] = v.x;
      w2t[(4*q+1)*129 + r] = v.y;
      w2t[(4*q+2)*129 + r] = v.z;
      w2t[(4*q+3)*129 + r] = v.w;
    }
  }
  __syncthreads();
  float acc = b1[h];
  #pragma unroll 8
  for (int d0 = 0; d0 < DD; ++d0) acc += xs[g][d0] * W1[d0*H + h];   // coalesced
  float a1 = tanhf(acc);
  a1s[g][h] = a1; A1[s*H + h] = a1;
  __syncthreads();
  acc = b2[h];
  #pragma unroll 8
  for (int d0 = 0; d0 < H; ++d0) acc += a1s[g][d0] * w2t[h*129 + d0];  // conflict-free
  float a2 = tanhf(acc);
  A2[s*H + h] = a2;
  float t2 = 1.0f - a2*a2;
  float g2v[CC];
  #pragma unroll
  for (int c = 0; c < CC; ++c) {
    g2v[c] = W3[h*CC + c] * t2;
    g2s[g][c*H + h] = g2v[c];
    G2[(s*CC + c)*H + h] = g2v[c];
  }
  __syncthreads();
  float t1 = 1.0f - a1*a1;
  float accs[CC];
  #pragma unroll
  for (int c = 0; c < CC; ++c) accs[c] = 0.0f;
  #pragma unroll 4
  for (int k = 0; k < H; ++k) {
    float w = w2t[k*129 + h];      // W2[h][k], conflict-free; g2s broadcast
    #pragma unroll
    for (int c = 0; c < CC; ++c) accs[c] += w * g2s[g][c*H + k];
  }
  #pragma unroll
  for (int c = 0; c < CC; ++c) G1[(s*CC + c)*H + h] = t1 * accs[c];
  // ---- fused Kxx_diag for test samples (b>=192 -> s>=384), single barrier ----
  if (b >= 192) {
    WRED(xv*xv, 0) WRED(a1*a1, 1) WRED(a2*a2, 2)
    #pragma unroll
    for (int c = 0; c < CC; ++c) {
      float g1v = t1 * accs[c];
      WRED(g1v*g1v, 3+2*c)
      WRED(g2v[c]*g2v[c], 4+2*c)
    }
    __syncthreads();
    if (tid < 2*CC) {
      int gi = tid / CC, c = tid % CC;
      const float* P = partGA[gi];
      float nx  = P[0] + P[1];
      float na1 = P[2] + P[3];
      float na2 = P[4] + P[5];
      float n1 = P[(3+2*c)*2] + P[(3+2*c)*2+1];
      float n2 = P[(4+2*c)*2] + P[(4+2*c)*2+1];
      int t = 2*(b-192) + gi;
      out[TN*CC + t*CC + c] = SCALE * ((1.0f+nx)*n1 + (1.0f+na1)*n2 + (1.0f+na2));
    }
  }
}

// Class-independent base dot products: 1+x.x', 1+a1.a1', 1+a2.a2'
__global__ __launch_bounds__(256) void k_base(const float* __restrict__ XS,
    const float* __restrict__ A1, const float* __restrict__ A2, float* __restrict__ Base)
{
  int set = blockIdx.z;
  int colsN = (set == 0) ? NX : MZ;
  if ((int)blockIdx.x * 16 >= colsN) return;
  int rowOff = (set == 2) ? NX+MZ : NX;
  int colOff = (set == 0) ? 0 : NX;
  unsigned baseOff = (set == 0) ? BASE_ZX : (set == 1 ? BASE_ZZ : BASE_TZ);
  __shared__ float rx[16*132], r1[16*132], r2[16*132], cxs[16*132], c1s[16*132], c2s[16*132];
  int tid = threadIdx.x, m0 = blockIdx.y*16, n0 = blockIdx.x*16;
  for (int idx = tid; idx < 16*128; idx += 256) {
    int r = idx >> 7, hh = idx & 127;
    int sr = rowOff + m0 + r, sc = colOff + n0 + r;
    rx [r*132+hh] = XS[sr*DD+hh]; r1[r*132+hh] = A1[sr*H+hh]; r2[r*132+hh] = A2[sr*H+hh];
    cxs[r*132+hh] = XS[sc*DD+hh]; c1s[r*132+hh] = A1[sc*H+hh]; c2s[r*132+hh] = A2[sc*H+hh];
  }
  __syncthreads();
  int ty = tid >> 4, tx = tid & 15;
  const float4* pa = (const float4*)(rx  + ty*132);
  const float4* pb = (const float4*)(cxs + tx*132);
  const float4* pc = (const float4*)(r1  + ty*132);
  const float4* pd = (const float4*)(c1s + tx*132);
  const float4* pe = (const float4*)(r2  + ty*132);
  const float4* pf = (const float4*)(c2s + tx*132);
  float d0 = 0, d1 = 0, d2 = 0;
  #pragma unroll 8
  for (int q = 0; q < 32; ++q) {
    float4 a = pa[q], b = pb[q]; d0 += a.x*b.x + a.y*b.y + a.z*b.z + a.w*b.w;
    float4 c = pc[q], d = pd[q]; d1 += c.x*d.x + c.y*d.y + c.z*d.z + c.w*d.w;
    float4 e = pe[q], f = pf[q]; d2 += e.x*f.x + e.y*f.y + e.z*f.z + e.w*f.w;
  }
  int m = m0 + ty, n = n0 + tx;
  float* Bp = Base + baseOff;
  int area = 128 * colsN;
  Bp[0*area + m*colsN + n] = 1.0f + d0;
  Bp[1*area + m*colsN + n] = 1.0f + d1;
  Bp[2*area + m*colsN + n] = 1.0f + d2;
}

// Per-class NTK gram, 32x32 tiles, 2x2 outputs/thread (halves LDS traffic and
// staging bytes per output vs 16x16). set==0 folds LamU via shfl+atomics.
__global__ __launch_bounds__(256) void k_gram(const float* __restrict__ G1, const float* __restrict__ G2,
    const float* __restrict__ Base, const float* __restrict__ Y,
    float* __restrict__ Kzx, float* __restrict__ Kzz, float* __restrict__ Kxz,
    float* __restrict__ LamU)
{
  int z = blockIdx.z, set = z / CC, c = z % CC;
  int colsN = (set == 0) ? NX : MZ;
  if ((int)blockIdx.x * 32 >= colsN) return;
  int rowOff = (set == 2) ? NX+MZ : NX;
  int colOff = (set == 0) ? 0 : NX;
  unsigned baseOff = (set == 0) ? BASE_ZX : (set == 1 ? BASE_ZZ : BASE_TZ);
  float* outp = (set == 0) ? Kzx + c*MZ*NX : (set == 1 ? Kzz + c*MZ*MZ : Kxz + c*TN*MZ);
  __shared__ float g1r[32*132], g2r[32*132], g1c[32*132], g2c[32*132];
  int tid = threadIdx.x, m0 = blockIdx.y*32, n0 = blockIdx.x*32;
  for (int idx = tid; idx < 32*128; idx += 256) {
    int r = idx >> 7, hh = idx & 127;
    int sr = rowOff + m0 + r, sc = colOff + n0 + r;
    g1r[r*132+hh] = G1[(sr*CC + c)*H + hh]; g2r[r*132+hh] = G2[(sr*CC + c)*H + hh];
    g1c[r*132+hh] = G1[(sc*CC + c)*H + hh]; g2c[r*132+hh] = G2[(sc*CC + c)*H + hh];
  }
  __syncthreads();
  int ty = tid >> 4, tx = tid & 15;
  // rows ty, ty+16 ; cols tx, tx+16
  const float4* a0p = (const float4*)(g1r + ty*132);
  const float4* a1p = (const float4*)(g1r + (ty+16)*132);
  const float4* b0p = (const float4*)(g1c + tx*132);
  const float4* b1p = (const float4*)(g1c + (tx+16)*132);
  const float4* e0p = (const float4*)(g2r + ty*132);
  const float4* e1p = (const float4*)(g2r + (ty+16)*132);
  const float4* f0p = (const float4*)(g2c + tx*132);
  const float4* f1p = (const float4*)(g2c + (tx+16)*132);
  float d1_00=0, d1_01=0, d1_10=0, d1_11=0;
  float d2_00=0, d2_01=0, d2_10=0, d2_11=0;
  #pragma unroll 4
  for (int q = 0; q < 32; ++q) {
    float4 a0 = a0p[q], a1 = a1p[q], b0 = b0p[q], b1 = b1p[q];
    d1_00 += a0.x*b0.x + a0.y*b0.y + a0.z*b0.z + a0.w*b0.w;
    d1_01 += a0.x*b1.x + a0.y*b1.y + a0.z*b1.z + a0.w*b1.w;
    d1_10 += a1.x*b0.x + a1.y*b0.y + a1.z*b0.z + a1.w*b0.w;
    d1_11 += a1.x*b1.x + a1.y*b1.y + a1.z*b1.z + a1.w*b1.w;
    float4 e0 = e0p[q], e1 = e1p[q], f0 = f0p[q], f1 = f1p[q];
    d2_00 += e0.x*f0.x + e0.y*f0.y + e0.z*f0.z + e0.w*f0.w;
    d2_01 += e0.x*f1.x + e0.y*f1.y + e0.z*f1.z + e0.w*f1.w;
    d2_10 += e1.x*f0.x + e1.y*f0.y + e1.z*f0.z + e1.w*f0.w;
    d2_11 += e1.x*f1.x + e1.y*f1.y + e1.z*f1.z + e1.w*f1.w;
  }
  const float* Bp = Base + baseOff;
  int area = 128 * colsN;
  int mA = m0 + ty, mB = m0 + ty + 16, nA = n0 + tx, nB = n0 + tx + 16;
  float v00, v01, v10, v11;
  {
    float b0v = Bp[mA*colsN + nA], b1v = Bp[area + mA*colsN + nA], b2v = Bp[2*area + mA*colsN + nA];
    v00 = SCALE * (b0v*d1_00 + b1v*d2_00 + b2v);
    b0v = Bp[mA*colsN + nB]; b1v = Bp[area + mA*colsN + nB]; b2v = Bp[2*area + mA*colsN + nB];
    v01 = SCALE * (b0v*d1_01 + b1v*d2_01 + b2v);
    b0v = Bp[mB*colsN + nA]; b1v = Bp[area + mB*colsN + nA]; b2v = Bp[2*area + mB*colsN + nA];
    v10 = SCALE * (b0v*d1_10 + b1v*d2_10 + b2v);
    b0v = Bp[mB*colsN + nB]; b1v = Bp[area + mB*colsN + nB]; b2v = Bp[2*area + mB*colsN + nB];
    v11 = SCALE * (b0v*d1_11 + b1v*d2_11 + b2v);
  }
  outp[mA*colsN + nA] = v00;
  outp[mA*colsN + nB] = v01;
  outp[mB*colsN + nA] = v10;
  outp[mB*colsN + nB] = v11;
  if (set == 0) {
    float lamA = v00 * Y[nA*CC + c] + v01 * Y[nB*CC + c];
    float lamB = v10 * Y[nA*CC + c] + v11 * Y[nB*CC + c];
    lamA += __shfl_xor(lamA, 1, 64); lamA += __shfl_xor(lamA, 2, 64);
    lamA += __shfl_xor(lamA, 4, 64); lamA += __shfl_xor(lamA, 8, 64);
    lamB += __shfl_xor(lamB, 1, 64); lamB += __shfl_xor(lamB, 2, 64);
    lamB += __shfl_xor(lamB, 4, 64); lamB += __shfl_xor(lamB, 8, 64);
    if (tx == 0) {
      atomicAdd(&LamU[c*MZ + mA], lamA * INV_S2);
      atomicAdd(&LamU[c*MZ + mB], lamB * INV_S2);
    }
  }
}

// KzzB = Kzz + Kzx Kzx^T + 2*JIT*I ; Kzzj = Kzz + JIT*I  (single-barrier)
__global__ __launch_bounds__(256) void k_kzzb(const float* __restrict__ Kzx, const float* __restrict__ Kzz,
    float* __restrict__ Kzzj, float* __restrict__ KzzB)
{
  int c = blockIdx.z, m0 = blockIdx.y*16, k0 = blockIdx.x*16;
  int tid = threadIdx.x, ty = tid >> 4, tx = tid & 15;
  __shared__ float Am[16*260], Ak[16*260];
  const float* Kc = Kzx + c*MZ*NX;
  const float4* src_m = (const float4*)(Kc + m0*NX);
  const float4* src_k = (const float4*)(Kc + k0*NX);
  float4* Am4 = (float4*)Am;   // stride 65 float4 per row
  float4* Ak4 = (float4*)Ak;
  for (int idx = tid; idx < 16*64; idx += 256) {
    int r = idx >> 6, q = idx & 63;
    Am4[r*65 + q] = src_m[r*64 + q];
    Ak4[r*65 + q] = src_k[r*64 + q];
  }
  __syncthreads();
  const float4* am = (const float4*)(Am + ty*260);
  const float4* ak = (const float4*)(Ak + tx*260);
  float acc = 0;
  #pragma unroll 8
  for (int q = 0; q < 64; ++q) {
    float4 a = am[q], b = ak[q];
    acc += a.x*b.x + a.y*b.y + a.z*b.z + a.w*b.w;
  }
  int m = m0+ty, k = k0+tx, idx = c*MZ*MZ + m*MZ + k;
  float kzz = Kzz[idx];
  float dia = (m == k) ? 1.0f : 0.0f;
  Kzzj[idx] = kzz + dia*JIT;
  KzzB[idx] = kzz + acc*INV_S2 + dia*2.0f*JIT;
}

// Blocked (rank-4) Cholesky + folded ylam forward-subst, float4-vectorized
// triangular trailing update. Emits strictly-lower Lc, invd, ylam (which==1).
__global__ __launch_bounds__(512) void k_chol(const float* __restrict__ Kzzj, const float* __restrict__ KzzB,
    float* __restrict__ Lc, float* __restrict__ invd,
    const float* __restrict__ LamU, float* __restrict__ ylam)
{
  int which = blockIdx.x & 1, c = blockIdx.x >> 1;
  const float* Ain = (which ? KzzB : Kzzj) + c*MZ*MZ;
  float* LcB = Lc + (size_t)(which*CC + c)*MZ*MZ;
  float* invB = invd + (which*CC + c)*MZ;
  __shared__ float As[MZ*MZ];
  __shared__ float4 pan[MZ];
  __shared__ float bs[MZ];
  __shared__ float ys[MZ];
  int tid = threadIdx.x;
  int rg = tid & 31, kp = tid >> 5;
  float4* As4 = (float4*)As;
  {
    float4* d4 = (float4*)As; const float4* s4 = (const float4*)Ain;
    #pragma unroll
    for (int r = 0; r < 8; ++r) d4[tid + 512*r] = s4[tid + 512*r];
  }
  if (tid < MZ) bs[tid] = which ? LamU[c*MZ + tid] : 0.0f;
  __syncthreads();
  for (int jb = 0; jb < 32; ++jb) {
    int j = jb*4;
    if (tid < MZ) {
      int i = tid;
      float r0 = As[(j+0)*MZ + i], r1 = As[(j+1)*MZ + i], r2 = As[(j+2)*MZ + i], r3 = As[(j+3)*MZ + i];
      float a00 = As[j*MZ+j];
      float a10 = As[j*MZ+j+1], a20 = As[j*MZ+j+2], a30 = As[j*MZ+j+3];
      float a11 = As[(j+1)*MZ+j+1], a21 = As[(j+1)*MZ+j+2], a31 = As[(j+1)*MZ+j+3];
      float a22 = As[(j+2)*MZ+j+2], a32 = As[(j+2)*MZ+j+3];
      float a33 = As[(j+3)*MZ+j+3];
      float bj0 = bs[j], bj1 = bs[j+1], bj2 = bs[j+2], bj3 = bs[j+3];
      float id0 = rsqrtf(a00);
      float l10 = a10*id0, l20 = a20*id0, l30 = a30*id0;
      float id1 = rsqrtf(a11 - l10*l10);
      float l21 = (a21 - l20*l10)*id1, l31 = (a31 - l30*l10)*id1;
      float id2 = rsqrtf(a22 - l20*l20 - l21*l21);
      float l32 = (a32 - l30*l20 - l31*l21)*id2;
      float id3 = rsqrtf(a33 - l30*l30 - l31*l31 - l32*l32);
      float c0 = r0*id0;
      float c1 = (r1 - c0*l10)*id1;
      float c2 = (r2 - c0*l20 - c1*l21)*id2;
      float c3 = (r3 - c0*l30 - c1*l31 - c2*l32)*id3;
      float y0 = bj0*id0;
      float y1 = (bj1 - l10*y0)*id1;
      float y2 = (bj2 - l20*y0 - l21*y1)*id2;
      float y3 = (bj3 - l30*y0 - l31*y1 - l32*y2)*id3;
      pan[i] = make_float4(c0, c1, c2, c3);
      LcB[(j+0)*MZ + i] = (i > j+0) ? c0 : 0.0f;
      LcB[(j+1)*MZ + i] = (i > j+1) ? c1 : 0.0f;
      LcB[(j+2)*MZ + i] = (i > j+2) ? c2 : 0.0f;
      LcB[(j+3)*MZ + i] = (i > j+3) ? c3 : 0.0f;
      if (i == j) {
        invB[j] = id0; invB[j+1] = id1; invB[j+2] = id2; invB[j+3] = id3;
        ys[j] = y0; ys[j+1] = y1; ys[j+2] = y2; ys[j+3] = y3;
      }
      if (i >= j+4) bs[i] -= c0*y0 + c1*y1 + c2*y2 + c3*y3;
    }
    __syncthreads();
    float4 p0 = pan[4*rg+0], p1 = pan[4*rg+1], p2 = pan[4*rg+2], p3 = pan[4*rg+3];
    int kstart = (j + 4) + ((kp - (j + 4)) & 15);
    int kend = 4*rg + 3;
    for (int k = kstart; k <= kend; k += 16) {
      float4 ck = pan[k];
      float4 a4 = As4[k*32 + rg];
      a4.x -= p0.x*ck.x + p0.y*ck.y + p0.z*ck.z + p0.w*ck.w;
      a4.y -= p1.x*ck.x + p1.y*ck.y + p1.z*ck.z + p1.w*ck.w;
      a4.z -= p2.x*ck.x + p2.y*ck.y + p2.z*ck.z + p2.w*ck.w;
      a4.w -= p3.x*ck.x + p3.y*ck.y + p3.z*ck.z + p3.w*ck.w;
      As4[k*32 + rg] = a4;
    }
    __syncthreads();
  }
  if (which && tid < MZ) ylam[c*MZ + tid] = ys[tid];
}

// Forward substitution L W = Kzxt, wave-distributed columns; finalizes output
// (lane 0: atomicAdd ±sum(W^2) onto Kxxd base; which==1 writes f_mean).
__device__ __forceinline__ float rdlane(float v, int lane) {
  return __int_as_float(__builtin_amdgcn_readlane(__float_as_int(v), lane));
}

__global__ __launch_bounds__(512) void k_solve(const float* __restrict__ Lc,
    const float* __restrict__ invd, const float* __restrict__ ylam,
    const float* __restrict__ Kxz, float* __restrict__ out)
{
  int quarter = blockIdx.x & 3;
  int which   = (blockIdx.x >> 2) & 1;
  int c       = blockIdx.x >> 3;
  const float2* LcB2 = (const float2*)(Lc + (size_t)(which*CC + c)*MZ*MZ);
  const float2* invB2 = (const float2*)(invd + (which*CC + c)*MZ);
  const float2* ylB2  = (const float2*)(ylam + c*MZ);
  int tid = threadIdx.x, l = tid & 63, wv = tid >> 6;
  __shared__ float2 Ls[MZ*64];
  #pragma unroll
  for (int r = 0; r < 16; ++r) Ls[tid + 512*r] = LcB2[tid + 512*r];
  float2 iv = invB2[l];
  float2 yl = ylB2[l];
  int col0 = quarter*32 + wv*4;
  const float* K0 = Kxz + (size_t)c*TN*MZ;
  float2 b0 = *(const float2*)(K0 + (size_t)(col0+0)*MZ + 2*l);
  float2 b1 = *(const float2*)(K0 + (size_t)(col0+1)*MZ + 2*l);
  float2 b2 = *(const float2*)(K0 + (size_t)(col0+2)*MZ + 2*l);
  float2 b3 = *(const float2*)(K0 + (size_t)(col0+3)*MZ + 2*l);
  __syncthreads();
  #pragma unroll
  for (int j = 0; j < MZ; ++j) {
    const int owner = j >> 1;
    float2 Lj = Ls[j*64 + l];
    float y0, y1, y2, y3;
    if ((j & 1) == 0) {
      y0 = rdlane(b0.x * iv.x, owner);
      y1 = rdlane(b1.x * iv.x, owner);
      y2 = rdlane(b2.x * iv.x, owner);
      y3 = rdlane(b3.x * iv.x, owner);
    } else {
      y0 = rdlane(b0.y * iv.y, owner);
      y1 = rdlane(b1.y * iv.y, owner);
      y2 = rdlane(b2.y * iv.y, owner);
      y3 = rdlane(b3.y * iv.y, owner);
    }
    b0.x -= Lj.x * y0; b0.y -= Lj.y * y0;
    b1.x -= Lj.x * y1; b1.y -= Lj.y * y1;
    b2.x -= Lj.x * y2; b2.y -= Lj.y * y2;
    b3.x -= Lj.x * y3; b3.y -= Lj.y * y3;
    if (l == owner) {
      if ((j & 1) == 0) { b0.x = y0; b1.x = y1; b2.x = y2; b3.x = y3; }
      else              { b0.y = y0; b1.y = y1; b2.y = y2; b3.y = y3; }
    }
  }
  float sq0 = b0.x*b0.x + b0.y*b0.y, fm0 = b0.x*yl.x + b0.y*yl.y;
  float sq1 = b1.x*b1.x + b1.y*b1.y, fm1 = b1.x*yl.x + b1.y*yl.y;
  float sq2 = b2.x*b2.x + b2.y*b2.y, fm2 = b2.x*yl.x + b2.y*yl.y;
  float sq3 = b3.x*b3.x + b3.y*b3.y, fm3 = b3.x*yl.x + b3.y*yl.y;
  #pragma unroll
  for (int off = 32; off > 0; off >>= 1) {
    sq0 += __shfl_xor(sq0, off, 64); fm0 += __shfl_xor(fm0, off, 64);
    sq1 += __shfl_xor(sq1, off, 64); fm1 += __shfl_xor(fm1, off, 64);
    sq2 += __shfl_xor(sq2, off, 64); fm2 += __shfl_xor(fm2, off, 64);
    sq3 += __shfl_xor(sq3, off, 64); fm3 += __shfl_xor(fm3, off, 64);
  }
  if (l == 0) {
    float sgn = which ? 1.0f : -1.0f;
    float* var = out + TN*CC;
    atomicAdd(&var[(col0+0)*CC + c], sgn*sq0);
    atomicAdd(&var[(col0+1)*CC + c], sgn*sq1);
    atomicAdd(&var[(col0+2)*CC + c], sgn*sq2);
    atomicAdd(&var[(col0+3)*CC + c], sgn*sq3);
    if (which) {
      out[(col0+0)*CC + c] = fm0;
      out[(col0+1)*CC + c] = fm1;
      out[(col0+2)*CC + c] = fm2;
      out[(col0+3)*CC + c] = fm3;
    }
  }
}

extern "C" void kernel_launch(void* const* d_in, const int* in_sizes, int n_in,
                              void* d_out, int out_size, void* d_ws, size_t ws_size,
                              hipStream_t stream) {
  (void)in_sizes; (void)n_in; (void)out_size; (void)ws_size;
  const float* X  = (const float*)d_in[0];
  const float* Y  = (const float*)d_in[1];
  const float* Z  = (const float*)d_in[2];
  const float* Xt = (const float*)d_in[3];
  const float* W1 = (const float*)d_in[4];
  const float* b1 = (const float*)d_in[5];
  const float* W2 = (const float*)d_in[6];
  const float* b2 = (const float*)d_in[7];
  const float* W3 = (const float*)d_in[8];
  float* ws  = (float*)d_ws;
  float* out = (float*)d_out;

  float* XS   = ws + OFF_XS;
  float* A1   = ws + OFF_A1;
  float* A2   = ws + OFF_A2;
  float* G1   = ws + OFF_G1;
  float* G2   = ws + OFF_G2;
  float* Base = ws + OFF_BASE;
  float* Kzx  = ws + OFF_KZX;
  float* Kzz  = ws + OFF_KZZ;
  float* Kxz  = ws + OFF_KXZ;
  float* Kzzj = ws + OFF_KZZJ;
  float* KzzB = ws + OFF_KZZB;
  float* LamU = ws + OFF_LAMU;
  float* Lc   = ws + OFF_LC;
  float* invd = ws + OFF_INVD;
  float* ylam = ws + OFF_YLAM;

  k_features<<<S_TOT/2, 256, 0, stream>>>(X, Z, Xt, W1, b1, W2, b2, W3, XS, A1, A2, G1, G2, LamU, out);
  k_base<<<dim3(16, 8, 3), 256, 0, stream>>>(XS, A1, A2, Base);
  k_gram<<<dim3(8, 4, 3*CC), 256, 0, stream>>>(G1, G2, Base, Y, Kzx, Kzz, Kxz, LamU);
  k_kzzb<<<dim3(8, 8, CC), 256, 0, stream>>>(Kzx, Kzz, Kzzj, KzzB);
  k_chol<<<2*CC, 512, 0, stream>>>(Kzzj, KzzB, Lc, invd, LamU, ylam);
  k_solve<<<8*CC, 512, 0, stream>>>(Lc, invd, ylam, Kxz, out);
}